// Round 1
// baseline (71.108 us; speedup 1.0000x reference)
//
#include <hip/hip_runtime.h>
#include <math.h>

#define N_WAVES 128
#define BLOCK 256
#define PPT 2   // points per thread

// out[n] = sum_w  c0*sin(2pi*f*(x0*cos r + x1*sin r)) + c1*cos(...)
//        = sum_w  R_w * sin(2pi*(a_w*x0 + b_w*x1) + phi_w)
// with a = f*cos r, b = f*sin r, R = hypot(c0,c1), phi = atan2(c1,c0).
// v_sin_f32 computes sin(2pi * x) with x in revolutions -> phase kept in revs.

__global__ __launch_bounds__(BLOCK) void periodic2d_kernel(
    const float* __restrict__ x,      // [N,2]
    const float* __restrict__ freqs,  // [W]
    const float* __restrict__ rots,   // [W]
    const float* __restrict__ coeffs, // [W,2]
    float* __restrict__ out,          // [N]
    int n)
{
    __shared__ float4 wp[N_WAVES];  // {a, b, phi_rev, amp}

    const int tid = threadIdx.x;
    if (tid < N_WAVES) {
        float f  = freqs[tid];
        float r  = rots[tid];
        float c0 = coeffs[2 * tid];
        float c1 = coeffs[2 * tid + 1];
        float sr, cr;
        sincosf(r, &sr, &cr);                    // setup-only: accurate path
        float amp = sqrtf(c0 * c0 + c1 * c1);
        float phi = atan2f(c1, c0) * 0.15915494309189535f;  // radians -> revs
        wp[tid] = make_float4(f * cr, f * sr, phi, amp);
    }
    __syncthreads();

    const int ia = blockIdx.x * (BLOCK * PPT) + tid;
    const int ib = ia + BLOCK;

    const float2* __restrict__ X2 = (const float2*)x;
    float x0a = 0.f, x1a = 0.f, x0b = 0.f, x1b = 0.f;
    if (ia < n) { float2 v = X2[ia]; x0a = v.x; x1a = v.y; }
    if (ib < n) { float2 v = X2[ib]; x0b = v.x; x1b = v.y; }

    float acca = 0.f, accb = 0.f;
#pragma unroll 8
    for (int w = 0; w < N_WAVES; ++w) {
        float4 p = wp[w];
        // point A
        float pa = __builtin_fmaf(p.x, x0a, __builtin_fmaf(p.y, x1a, p.z));
        float ta = __builtin_amdgcn_fractf(pa);
        float sa = __builtin_amdgcn_sinf(ta);
        acca = __builtin_fmaf(p.w, sa, acca);
        // point B
        float pb = __builtin_fmaf(p.x, x0b, __builtin_fmaf(p.y, x1b, p.z));
        float tb = __builtin_amdgcn_fractf(pb);
        float sb = __builtin_amdgcn_sinf(tb);
        accb = __builtin_fmaf(p.w, sb, accb);
    }

    if (ia < n) out[ia] = acca;
    if (ib < n) out[ib] = accb;
}

extern "C" void kernel_launch(void* const* d_in, const int* in_sizes, int n_in,
                              void* d_out, int out_size, void* d_ws, size_t ws_size,
                              hipStream_t stream) {
    const float* x      = (const float*)d_in[0];
    const float* freqs  = (const float*)d_in[1];
    const float* rots   = (const float*)d_in[2];
    const float* coeffs = (const float*)d_in[3];
    float* out = (float*)d_out;

    const int n = out_size;  // 500,000 points
    const int grid = (n + BLOCK * PPT - 1) / (BLOCK * PPT);
    periodic2d_kernel<<<grid, BLOCK, 0, stream>>>(x, freqs, rots, coeffs, out, n);
}